// Round 20
// baseline (385.872 us; speedup 1.0000x reference)
//
#include <hip/hip_runtime.h>
#include <math.h>
#include <stdint.h>

#define NEG_SENT -1e30f

typedef __attribute__((ext_vector_type(8))) short bf16x8;
typedef __attribute__((ext_vector_type(4))) float f32x4;

__device__ __forceinline__ unsigned short f2bf(float f) {
    unsigned u = __float_as_uint(f);
    unsigned r = u + 0x7FFFu + ((u >> 16) & 1u);   // round-to-nearest-even
    return (unsigned short)(r >> 16);
}
__device__ __forceinline__ float bf2f(unsigned short h) {
    return __uint_as_float(((unsigned)h) << 16);
}
// order-preserving float<->uint encoding (for atomicMax over signed floats)
__device__ __forceinline__ unsigned enc_f(float f) {
    unsigned u = __float_as_uint(f);
    return (u & 0x80000000u) ? ~u : (u | 0x80000000u);
}
__device__ __forceinline__ float dec_f(unsigned u) {
    unsigned v = (u & 0x80000000u) ? (u & 0x7FFFFFFFu) : ~u;
    return __uint_as_float(v);
}

// ---------- prep (fused): W1/W2 transpose->bf16  +  degree count ----------
__global__ __launch_bounds__(256) void prep_count(const float* __restrict__ w1,
        const float* __restrict__ w2, unsigned short* __restrict__ w1t,
        unsigned short* __restrict__ w2t, const int* __restrict__ ei,
        int E, int Etot, int* __restrict__ deg) {
    int b = blockIdx.x;
    if (b < 160) {
        int tidx = b * 256 + threadIdx.x;
        if (b < 128) {
            int k = tidx & 127, n = tidx >> 7;      // w1t[n][k]
            w1t[tidx] = f2bf(w1[k * 256 + n]);
        } else {
            int idx = tidx - 32768;                 // w2t[n][k]
            int k = idx & 255, n = idx >> 8;
            w2t[idx] = f2bf(w2[k * 32 + n]);
        }
    } else {
        int e = (b - 160) * 256 + threadIdx.x;
        if (e >= Etot) return;
        int d = (e < E) ? ei[E + e] : e - E;
        atomicAdd(&deg[d], 1);
    }
}

// ---------- layer-1 GEMM (bf16 MFMA) + fused projections + global a_s max ----------
__global__ __launch_bounds__(256) void gemm1_mfma(
        const float* __restrict__ x,
        const unsigned short* __restrict__ w1t,
        const float* __restrict__ att_s, const float* __restrict__ att_d,
        unsigned short* __restrict__ xph,
        float* __restrict__ a_s, float* __restrict__ a_d,
        unsigned* __restrict__ mgl, int M) {
    int wave = (int)(((long)blockIdx.x * 256 + threadIdx.x) >> 6);
    int lane = threadIdx.x & 63;
    int row0 = wave * 16;
    if (row0 >= M) return;
    int r = lane & 15;
    int g = lane >> 4;
    bf16x8 a[4];
    const float* arow = x + (long)(row0 + r) * 128 + g * 8;
    #pragma unroll
    for (int k0 = 0; k0 < 4; ++k0) {
        float4 f0 = *(const float4*)(arow + k0 * 32);
        float4 f1 = *(const float4*)(arow + k0 * 32 + 4);
        bf16x8 af;
        af[0] = (short)f2bf(f0.x); af[1] = (short)f2bf(f0.y);
        af[2] = (short)f2bf(f0.z); af[3] = (short)f2bf(f0.w);
        af[4] = (short)f2bf(f1.x); af[5] = (short)f2bf(f1.y);
        af[6] = (short)f2bf(f1.z); af[7] = (short)f2bf(f1.w);
        a[k0] = af;
    }
    float as_v[16], ad_v[16];
    #pragma unroll
    for (int nt = 0; nt < 16; ++nt) {
        as_v[nt] = att_s[nt * 16 + r];
        ad_v[nt] = att_d[nt * 16 + r];
    }
    f32x4 acc[16];
    #pragma unroll
    for (int nt = 0; nt < 16; ++nt) acc[nt] = (f32x4){0.f, 0.f, 0.f, 0.f};
    #pragma unroll
    for (int nt = 0; nt < 16; ++nt) {
        const unsigned short* brow = w1t + (long)(nt * 16 + r) * 128 + g * 8;
        #pragma unroll
        for (int k0 = 0; k0 < 4; ++k0) {
            bf16x8 b = *(const bf16x8*)(brow + k0 * 32);
            acc[nt] = __builtin_amdgcn_mfma_f32_16x16x32_bf16(a[k0], b, acc[nt], 0, 0, 0);
        }
    }
    float ps[4][4] = {};   // [q][head]
    float pd[4][4] = {};
    #pragma unroll
    for (int nt = 0; nt < 16; ++nt) {
        int hh = nt >> 2;
        #pragma unroll
        for (int q = 0; q < 4; ++q) {
            float v = acc[nt][q];
            xph[(long)(row0 + g * 4 + q) * 256 + nt * 16 + r] = f2bf(v);
            ps[q][hh] += v * as_v[nt];
            pd[q][hh] += v * ad_v[nt];
        }
    }
    #pragma unroll
    for (int off = 1; off < 16; off <<= 1) {
        #pragma unroll
        for (int q = 0; q < 4; ++q)
            #pragma unroll
            for (int hh = 0; hh < 4; ++hh) {
                ps[q][hh] += __shfl_xor(ps[q][hh], off);
                pd[q][hh] += __shfl_xor(pd[q][hh], off);
            }
    }
    if (r == 0) {
        #pragma unroll
        for (int q = 0; q < 4; ++q) {
            int row = row0 + g * 4 + q;
            #pragma unroll
            for (int hh = 0; hh < 4; ++hh) {
                a_s[row * 4 + hh] = ps[q][hh];
                a_d[row * 4 + hh] = pd[q][hh];
            }
        }
        #pragma unroll
        for (int hh = 0; hh < 4; ++hh) {
            float mx = fmaxf(fmaxf(ps[0][hh], ps[1][hh]),
                             fmaxf(ps[2][hh], ps[3][hh]));
            atomicMax(&mgl[hh], enc_f(mx));
        }
    }
}

// ---------- layer-2 GEMM (bf16 MFMA, bf16 xp2 out) + fused projections + max ----------
__global__ __launch_bounds__(256) void gemm2_mfma(
        const unsigned short* __restrict__ hb,
        const unsigned short* __restrict__ w2t,
        const float* __restrict__ att_s, const float* __restrict__ att_d,
        unsigned short* __restrict__ xp2h,
        float* __restrict__ a_s, float* __restrict__ a_d,
        unsigned* __restrict__ mgl, int M) {
    int wave = (int)(((long)blockIdx.x * 256 + threadIdx.x) >> 6);
    int lane = threadIdx.x & 63;
    int row0 = wave * 16;
    if (row0 >= M) return;
    int r = lane & 15;
    int g = lane >> 4;
    bf16x8 a[8];
    const unsigned short* arow = hb + (long)(row0 + r) * 256 + g * 8;
    #pragma unroll
    for (int k0 = 0; k0 < 8; ++k0)
        a[k0] = *(const bf16x8*)(arow + k0 * 32);
    float as_v[2], ad_v[2];
    #pragma unroll
    for (int nt = 0; nt < 2; ++nt) {
        as_v[nt] = att_s[nt * 16 + r];
        ad_v[nt] = att_d[nt * 16 + r];
    }
    f32x4 acc[2];
    acc[0] = (f32x4){0.f, 0.f, 0.f, 0.f};
    acc[1] = (f32x4){0.f, 0.f, 0.f, 0.f};
    #pragma unroll
    for (int nt = 0; nt < 2; ++nt) {
        const unsigned short* brow = w2t + (long)(nt * 16 + r) * 256 + g * 8;
        #pragma unroll
        for (int k0 = 0; k0 < 8; ++k0) {
            bf16x8 b = *(const bf16x8*)(brow + k0 * 32);
            acc[nt] = __builtin_amdgcn_mfma_f32_16x16x32_bf16(a[k0], b, acc[nt], 0, 0, 0);
        }
    }
    float ps[4] = {}, pd[4] = {};
    #pragma unroll
    for (int nt = 0; nt < 2; ++nt) {
        #pragma unroll
        for (int q = 0; q < 4; ++q) {
            float v = acc[nt][q];
            xp2h[(long)(row0 + g * 4 + q) * 32 + nt * 16 + r] = f2bf(v);
            ps[q] += v * as_v[nt];
            pd[q] += v * ad_v[nt];
        }
    }
    #pragma unroll
    for (int off = 1; off < 16; off <<= 1) {
        #pragma unroll
        for (int q = 0; q < 4; ++q) {
            ps[q] += __shfl_xor(ps[q], off);
            pd[q] += __shfl_xor(pd[q], off);
        }
    }
    if (r == 0) {
        #pragma unroll
        for (int q = 0; q < 4; ++q) {
            a_s[row0 + g * 4 + q] = ps[q];
            a_d[row0 + g * 4 + q] = pd[q];
        }
        float mx = fmaxf(fmaxf(ps[0], ps[1]), fmaxf(ps[2], ps[3]));
        atomicMax(&mgl[4], enc_f(mx));
    }
}

// ---------- CSR scan ----------
__global__ __launch_bounds__(256) void scan_local(const int* __restrict__ deg,
        int* __restrict__ rowptr, int* __restrict__ blocksum, int N) {
    __shared__ int part[256];
    int b = blockIdx.x, t = threadIdx.x;
    int base = b * 1024 + t * 4;
    int4 v = make_int4(0, 0, 0, 0);
    if (base + 3 < N) {
        v = *(const int4*)(deg + base);
    } else {
        if (base + 0 < N) v.x = deg[base + 0];
        if (base + 1 < N) v.y = deg[base + 1];
        if (base + 2 < N) v.z = deg[base + 2];
        if (base + 3 < N) v.w = deg[base + 3];
    }
    part[t] = v.x + v.y + v.z + v.w;
    __syncthreads();
    #pragma unroll
    for (int off = 1; off < 256; off <<= 1) {
        int val = (t >= off) ? part[t - off] : 0;
        __syncthreads();
        part[t] += val;
        __syncthreads();
    }
    if (t == 255) blocksum[b] = part[255];
    int r0 = (t > 0) ? part[t - 1] : 0;
    int r1 = r0 + v.x;
    int r2 = r1 + v.y;
    int r3 = r2 + v.z;
    if (base + 3 < N) {
        *(int4*)(rowptr + base) = make_int4(r0, r1, r2, r3);
    } else {
        if (base + 0 < N) rowptr[base + 0] = r0;
        if (base + 1 < N) rowptr[base + 1] = r1;
        if (base + 2 < N) rowptr[base + 2] = r2;
        if (base + 3 < N) rowptr[base + 3] = r3;
    }
}

__global__ __launch_bounds__(256) void scan_add(int* __restrict__ rowptr,
        const int* __restrict__ blocksum, int* __restrict__ cursor,
        int N, int Etot, int nb) {
    __shared__ int part[256];
    int b = blockIdx.x, t = threadIdx.x;
    part[t] = (t < nb) ? blocksum[t] : 0;
    __syncthreads();
    #pragma unroll
    for (int off = 1; off < 256; off <<= 1) {
        int val = (t >= off) ? part[t - off] : 0;
        __syncthreads();
        part[t] += val;
        __syncthreads();
    }
    int off_b = (b > 0) ? part[b - 1] : 0;
    int base = b * 1024 + t * 4;
    if (base + 3 < N) {
        int4 v = *(const int4*)(rowptr + base);
        v.x += off_b; v.y += off_b; v.z += off_b; v.w += off_b;
        *(int4*)(rowptr + base) = v;
        *(int4*)(cursor + base) = v;
    } else {
        for (int i = 0; i < 4; ++i) {
            if (base + i < N) {
                int v = rowptr[base + i] + off_b;
                rowptr[base + i] = v;
                cursor[base + i] = v;
            }
        }
    }
    if (b == 0 && t == 0) rowptr[N] = Etot;
}

__global__ __launch_bounds__(256) void scatter_edges(const int* __restrict__ ei,
        int E, int Etot, int* __restrict__ cursor, int* __restrict__ csr_src) {
    int e = blockIdx.x * 256 + threadIdx.x;
    if (e >= Etot) return;
    int s, d;
    if (e < E) { s = ei[e]; d = ei[E + e]; } else { s = e - E; d = s; }
    int pos = atomicAdd(&cursor[d], 1);
    csr_src[pos] = s;
}

// ---------- layer-1: row-sort + single-sweep softmax (global max bound) + gather ----------
// wave per node, 4 nodes/block. m = leaky(max_all a_s[h] + ad) >= row max; since
// softmax is shift-invariant and bf16 is floating point, any upper bound works.
__global__ __launch_bounds__(256) void agg1_fused(const int* __restrict__ rowptr,
        int* __restrict__ csr_src, const float* __restrict__ a_s,
        const float* __restrict__ a_d, const unsigned* __restrict__ mgl,
        const ushort4* __restrict__ xph4,
        const float* __restrict__ bias, ushort4* __restrict__ hb4, int N) {
    __shared__ int shmem[4][512];   // 8 KB: sort scratch, then e-coeff buffer
    unsigned short (*cbuf)[1024] = (unsigned short (*)[1024])shmem;
    int t = threadIdx.x;
    int w = t >> 6;
    int lane = t & 63;
    int d = blockIdx.x * 4 + w;
    if (d >= N) return;            // wave-uniform exit
    int row0 = rowptr[d];
    int deg = rowptr[d + 1] - row0;

    // ---- canonicalize this row (ascending src) ----
    int sv = 0x7FFFFFFF;
    bool reg_sorted = (deg <= 64);
    if (reg_sorted) {
        if (lane < deg) sv = csr_src[row0 + lane];
        #pragma unroll
        for (int k = 2; k <= 64; k <<= 1) {
            for (int jj = k >> 1; jj > 0; jj >>= 1) {
                int u = __shfl_xor(sv, jj);
                bool up = ((lane & k) == 0);
                bool lower = ((lane & jj) == 0);
                int mn = min(sv, u), mx = max(sv, u);
                sv = (up == lower) ? mn : mx;
            }
        }
        if (lane < deg) csr_src[row0 + lane] = sv;     // agg2 reads sorted
    } else if (deg <= 256) {
        for (int j = lane; j < deg; j += 64) shmem[w][j] = csr_src[row0 + j];
        for (int it = 0; it < deg; ++it) {
            int start = it & 1;
            #pragma unroll
            for (int rep = 0; rep < 2; ++rep) {
                int k = start + 2 * lane + rep * 128;
                if (k + 1 < deg) {
                    int a = shmem[w][k], b = shmem[w][k + 1];
                    if (a > b) { shmem[w][k] = b; shmem[w][k + 1] = a; }
                }
            }
        }
        for (int j = lane; j < deg; j += 64) csr_src[row0 + j] = shmem[w][j];
    } else if (lane == 0) {
        for (int i = 1; i < deg; ++i) {
            int key = csr_src[row0 + i];
            int k = i - 1;
            while (k >= 0 && csr_src[row0 + k] > key) {
                csr_src[row0 + k + 1] = csr_src[row0 + k];
                --k;
            }
            csr_src[row0 + k + 1] = key;
        }
    }

    int h = lane & 3;
    int j0 = lane >> 2;
    float ad = a_d[d * 4 + h];
    float m = dec_f(mgl[h]) + ad;
    m = m > 0.f ? m : 0.2f * m;    // upper bound of row max (monotone leaky)
    int iters = (deg + 15) >> 4;   // wave-uniform sweep iteration count
    // single sweep: e = exp(l - m) -> LDS bf16, sum (converged shfl)
    float s = 0.f;
    for (int it = 0; it < iters; ++it) {
        int j = j0 + (it << 4);
        int jc = (j < deg) ? j : 0;
        int sn = reg_sorted ? __shfl(sv, jc) : csr_src[row0 + jc];
        if (j < deg) {
            float l = a_s[sn * 4 + h] + ad;
            l = l > 0.f ? l : 0.2f * l;
            float e = expf(l - m);
            if (j < 256) cbuf[w][j * 4 + h] = f2bf(e);
            s += e;
        }
    }
    #pragma unroll
    for (int off = 4; off <= 32; off <<= 1) s += __shfl_xor(s, off);
    float inv = 1.f / (s + 1e-16f);
    int hsel = lane >> 4;
    float m_h   = __shfl(m, hsel);
    float inv_h = __shfl(inv, hsel);
    float ad_h  = __shfl(ad, hsel);
    // phase 2: gather (uniform loops -> converged shfl)
    int cap = deg < 256 ? deg : 256;
    float4 acc = make_float4(0.f, 0.f, 0.f, 0.f);
    int j = 0;
    for (; j + 4 <= cap; j += 4) {
        int s0 = reg_sorted ? __shfl(sv, j + 0) : csr_src[row0 + j + 0];
        int s1 = reg_sorted ? __shfl(sv, j + 1) : csr_src[row0 + j + 1];
        int s2 = reg_sorted ? __shfl(sv, j + 2) : csr_src[row0 + j + 2];
        int s3 = reg_sorted ? __shfl(sv, j + 3) : csr_src[row0 + j + 3];
        float c0 = bf2f(cbuf[w][(j + 0) * 4 + hsel]);
        float c1 = bf2f(cbuf[w][(j + 1) * 4 + hsel]);
        float c2 = bf2f(cbuf[w][(j + 2) * 4 + hsel]);
        float c3 = bf2f(cbuf[w][(j + 3) * 4 + hsel]);
        ushort4 u0 = xph4[(long)s0 * 64 + lane];
        ushort4 u1 = xph4[(long)s1 * 64 + lane];
        ushort4 u2 = xph4[(long)s2 * 64 + lane];
        ushort4 u3 = xph4[(long)s3 * 64 + lane];
        acc.x += c0 * bf2f(u0.x); acc.y += c0 * bf2f(u0.y);
        acc.z += c0 * bf2f(u0.z); acc.w += c0 * bf2f(u0.w);
        acc.x += c1 * bf2f(u1.x); acc.y += c1 * bf2f(u1.y);
        acc.z += c1 * bf2f(u1.z); acc.w += c1 * bf2f(u1.w);
        acc.x += c2 * bf2f(u2.x); acc.y += c2 * bf2f(u2.y);
        acc.z += c2 * bf2f(u2.z); acc.w += c2 * bf2f(u2.w);
        acc.x += c3 * bf2f(u3.x); acc.y += c3 * bf2f(u3.y);
        acc.z += c3 * bf2f(u3.z); acc.w += c3 * bf2f(u3.w);
    }
    for (; j < deg; ++j) {
        int sn = reg_sorted ? __shfl(sv, j) : csr_src[row0 + j];
        float c;
        if (j < 256) {
            c = bf2f(cbuf[w][j * 4 + hsel]);
        } else {   // overflow fallback (deg > 256; not hit in practice)
            float l = a_s[sn * 4 + hsel] + ad_h;
            l = l > 0.f ? l : 0.2f * l;
            c = bf2f(f2bf(expf(l - m_h)));
        }
        ushort4 u = xph4[(long)sn * 64 + lane];
        acc.x += c * bf2f(u.x); acc.y += c * bf2f(u.y);
        acc.z += c * bf2f(u.z); acc.w += c * bf2f(u.w);
    }
    float4 b = ((const float4*)bias)[lane];
    float vx = acc.x * inv_h + b.x; vx = vx > 0.f ? vx : expm1f(vx);
    float vy = acc.y * inv_h + b.y; vy = vy > 0.f ? vy : expm1f(vy);
    float vz = acc.z * inv_h + b.z; vz = vz > 0.f ? vz : expm1f(vz);
    float vw = acc.w * inv_h + b.w; vw = vw > 0.f ? vw : expm1f(vw);
    ushort4 o;
    o.x = f2bf(vx); o.y = f2bf(vy); o.z = f2bf(vz); o.w = f2bf(vw);
    hb4[(long)d * 64 + lane] = o;
}

// ---------- layer-2: single-sweep softmax (global max) + gather + row softmax ----------
__global__ __launch_bounds__(256) void agg2_fused(const int* __restrict__ rowptr,
        const int* __restrict__ csr_src, const float* __restrict__ a_s,
        const float* __restrict__ a_d, const unsigned* __restrict__ mgl,
        const unsigned short* __restrict__ xp2h,
        const float* __restrict__ bias, float* __restrict__ out, int N) {
    __shared__ unsigned short ebuf[8][256];     // e bf16 (4 KB)
    int t = threadIdx.x;
    int w2 = t >> 5;
    int d = blockIdx.x * 8 + w2;
    if (d >= N) return;
    int c = t & 31;
    int row0 = rowptr[d];
    int deg = rowptr[d + 1] - row0;
    float ad = a_d[d];
    float m = dec_f(mgl[4]) + ad;
    m = m > 0.f ? m : 0.2f * m;
    // single sweep: e = exp(l - m), store bf16, sum
    float s = 0.f;
    for (int j = c; j < deg; j += 32) {
        int sn = csr_src[row0 + j];
        float l = a_s[sn] + ad;
        l = l > 0.f ? l : 0.2f * l;
        float e = expf(l - m);
        if (j < 256) ebuf[w2][j] = f2bf(e);
        s += e;
    }
    #pragma unroll
    for (int off = 1; off <= 16; off <<= 1) s += __shfl_xor(s, off, 32);
    float inv = 1.f / (s + 1e-16f);
    // phase 2: gather with unnormalized e; inv folded at end
    int cap = deg < 256 ? deg : 256;
    float acc = 0.f;
    int j = 0;
    for (; j + 4 <= cap; j += 4) {
        long e0 = row0 + j;
        int s0 = csr_src[e0 + 0];
        int s1 = csr_src[e0 + 1];
        int s2 = csr_src[e0 + 2];
        int s3 = csr_src[e0 + 3];
        float c0 = bf2f(ebuf[w2][j + 0]);
        float c1 = bf2f(ebuf[w2][j + 1]);
        float c2 = bf2f(ebuf[w2][j + 2]);
        float c3 = bf2f(ebuf[w2][j + 3]);
        float v0 = bf2f(xp2h[(long)s0 * 32 + c]);
        float v1 = bf2f(xp2h[(long)s1 * 32 + c]);
        float v2 = bf2f(xp2h[(long)s2 * 32 + c]);
        float v3 = bf2f(xp2h[(long)s3 * 32 + c]);
        acc += c0 * v0;
        acc += c1 * v1;
        acc += c2 * v2;
        acc += c3 * v3;
    }
    for (; j < deg; ++j) {
        long e = row0 + j;
        int sn = csr_src[e];
        float co;
        if (j < 256) {
            co = bf2f(ebuf[w2][j]);
        } else {
            float l = a_s[sn] + ad; l = l > 0.f ? l : 0.2f * l;
            co = bf2f(f2bf(expf(l - m)));
        }
        acc += co * bf2f(xp2h[(long)sn * 32 + c]);
    }
    float v = acc * inv + bias[c];
    float mx = v;
    #pragma unroll
    for (int off = 16; off; off >>= 1) mx = fmaxf(mx, __shfl_xor(mx, off, 32));
    float ex = expf(v - mx);
    float sm = ex;
    #pragma unroll
    for (int off = 16; off; off >>= 1) sm += __shfl_xor(sm, off, 32);
    out[(long)d * 32 + c] = ex / sm;
}

// ---------- host ----------
extern "C" void kernel_launch(void* const* d_in, const int* in_sizes, int n_in,
                              void* d_out, int out_size, void* d_ws, size_t ws_size,
                              hipStream_t stream) {
    const float* x   = (const float*)d_in[0];
    const int*   ei  = (const int*)d_in[1];
    const float* W1  = (const float*)d_in[2];
    const float* as1 = (const float*)d_in[3];
    const float* ad1 = (const float*)d_in[4];
    const float* b1  = (const float*)d_in[5];
    const float* W2  = (const float*)d_in[6];
    const float* as2 = (const float*)d_in[7];
    const float* ad2 = (const float*)d_in[8];
    const float* b2  = (const float*)d_in[9];
    float* out = (float*)d_out;

    const int N = in_sizes[0] / 128;     // 50000
    const int E = in_sizes[1] / 2;       // 640000
    const int Etot = E + N;              // + self loops

    // workspace layout (~60 MB, 16B-aligned blocks)
    unsigned short* xp1h = (unsigned short*)d_ws;        // N*256 bf16
    unsigned short* hb   = xp1h + (long)N * 256;         // N*256 bf16
    unsigned short* w1t  = hb + (long)N * 256;           // 32768 bf16
    unsigned short* w2t  = w1t + 32768;                  // 8192 bf16
    unsigned short* xp2h = w2t + 8192;                   // N*32 bf16
    float* a_s1   = (float*)(xp2h + (long)N * 32);       // N*4
    float* a_d1   = a_s1 + (long)N * 4;                  // N*4
    float* a_s2   = a_d1 + (long)N * 4;                  // N
    float* a_d2   = a_s2 + N;                            // N
    unsigned* mgl = (unsigned*)(a_d2 + N);               // 8 (enc 0 == very low)
    int* deg      = (int*)(mgl + 8);                     // N
    int* rowptr   = deg + N;                             // N+4 (padded)
    int* cursor   = rowptr + N + 4;                      // N
    int* csr_src  = cursor + N;                          // Etot
    int* blocksum = csr_src + Etot;                      // 256

    // zero mgl (enc(x) >= 0x007FFFFF for all finite x, so 0 acts as -inf) + deg
    hipMemsetAsync(mgl, 0, (8 + (size_t)N) * sizeof(int), stream);

    // ---- CSR build + weight prep ----
    int nbE = (Etot + 255) / 256;
    int nbS = (N + 1023) / 1024;
    prep_count<<<160 + nbE, 256, 0, stream>>>(W1, W2, w1t, w2t, ei, E, Etot, deg);
    scan_local<<<nbS, 256, 0, stream>>>(deg, rowptr, blocksum, N);
    scan_add<<<nbS, 256, 0, stream>>>(rowptr, blocksum, cursor, N, Etot, nbS);
    scatter_edges<<<nbE, 256, 0, stream>>>(ei, E, Etot, cursor, csr_src);

    int gemmBlocks = (((N + 15) / 16) + 3) / 4;   // 4 waves/block

    // ---- layer 1 (agg1 canonicalizes csr_src rows in-kernel) ----
    gemm1_mfma<<<gemmBlocks, 256, 0, stream>>>(x, w1t, as1, ad1,
                                               xp1h, a_s1, a_d1, mgl, N);
    agg1_fused<<<(N + 3) / 4, 256, 0, stream>>>(rowptr, csr_src, a_s1, a_d1, mgl,
                                                (const ushort4*)xp1h, b1,
                                                (ushort4*)hb, N);

    // ---- layer 2 ----
    gemm2_mfma<<<gemmBlocks, 256, 0, stream>>>(hb, w2t, as2, ad2,
                                               xp2h, a_s2, a_d2, mgl, N);
    agg2_fused<<<(N + 7) / 8, 256, 0, stream>>>(rowptr, csr_src, a_s2, a_d2, mgl,
                                                xp2h, b2, out, N);
}

// Round 21
// 226.075 us; speedup vs baseline: 1.7068x; 1.7068x over previous
//
#include <hip/hip_runtime.h>
#include <math.h>
#include <stdint.h>

#define NEG_SENT -1e30f

typedef __attribute__((ext_vector_type(8))) short bf16x8;
typedef __attribute__((ext_vector_type(4))) float f32x4;

__device__ __forceinline__ unsigned short f2bf(float f) {
    unsigned u = __float_as_uint(f);
    unsigned r = u + 0x7FFFu + ((u >> 16) & 1u);   // round-to-nearest-even
    return (unsigned short)(r >> 16);
}
__device__ __forceinline__ float bf2f(unsigned short h) {
    return __uint_as_float(((unsigned)h) << 16);
}

// ---------- prep (fused): W1/W2 transpose->bf16  +  degree count ----------
__global__ __launch_bounds__(256) void prep_count(const float* __restrict__ w1,
        const float* __restrict__ w2, unsigned short* __restrict__ w1t,
        unsigned short* __restrict__ w2t, const int* __restrict__ ei,
        int E, int Etot, int* __restrict__ deg) {
    int b = blockIdx.x;
    if (b < 160) {
        int tidx = b * 256 + threadIdx.x;
        if (b < 128) {
            int k = tidx & 127, n = tidx >> 7;      // w1t[n][k]
            w1t[tidx] = f2bf(w1[k * 256 + n]);
        } else {
            int idx = tidx - 32768;                 // w2t[n][k]
            int k = idx & 255, n = idx >> 8;
            w2t[idx] = f2bf(w2[k * 32 + n]);
        }
    } else {
        int e = (b - 160) * 256 + threadIdx.x;
        if (e >= Etot) return;
        int d = (e < E) ? ei[E + e] : e - E;
        atomicAdd(&deg[d], 1);
    }
}

// ---------- layer-1 GEMM (bf16 MFMA) + fused projections ----------
__global__ __launch_bounds__(256) void gemm1_mfma(
        const float* __restrict__ x,
        const unsigned short* __restrict__ w1t,
        const float* __restrict__ att_s, const float* __restrict__ att_d,
        unsigned short* __restrict__ xph,
        float* __restrict__ a_s, float* __restrict__ a_d, int M) {
    int wave = (int)(((long)blockIdx.x * 256 + threadIdx.x) >> 6);
    int lane = threadIdx.x & 63;
    int row0 = wave * 16;
    if (row0 >= M) return;
    int r = lane & 15;
    int g = lane >> 4;
    bf16x8 a[4];
    const float* arow = x + (long)(row0 + r) * 128 + g * 8;
    #pragma unroll
    for (int k0 = 0; k0 < 4; ++k0) {
        float4 f0 = *(const float4*)(arow + k0 * 32);
        float4 f1 = *(const float4*)(arow + k0 * 32 + 4);
        bf16x8 af;
        af[0] = (short)f2bf(f0.x); af[1] = (short)f2bf(f0.y);
        af[2] = (short)f2bf(f0.z); af[3] = (short)f2bf(f0.w);
        af[4] = (short)f2bf(f1.x); af[5] = (short)f2bf(f1.y);
        af[6] = (short)f2bf(f1.z); af[7] = (short)f2bf(f1.w);
        a[k0] = af;
    }
    float as_v[16], ad_v[16];
    #pragma unroll
    for (int nt = 0; nt < 16; ++nt) {
        as_v[nt] = att_s[nt * 16 + r];
        ad_v[nt] = att_d[nt * 16 + r];
    }
    f32x4 acc[16];
    #pragma unroll
    for (int nt = 0; nt < 16; ++nt) acc[nt] = (f32x4){0.f, 0.f, 0.f, 0.f};
    #pragma unroll
    for (int nt = 0; nt < 16; ++nt) {
        const unsigned short* brow = w1t + (long)(nt * 16 + r) * 128 + g * 8;
        #pragma unroll
        for (int k0 = 0; k0 < 4; ++k0) {
            bf16x8 b = *(const bf16x8*)(brow + k0 * 32);
            acc[nt] = __builtin_amdgcn_mfma_f32_16x16x32_bf16(a[k0], b, acc[nt], 0, 0, 0);
        }
    }
    float ps[4][4] = {};   // [q][head]
    float pd[4][4] = {};
    #pragma unroll
    for (int nt = 0; nt < 16; ++nt) {
        int hh = nt >> 2;
        #pragma unroll
        for (int q = 0; q < 4; ++q) {
            float v = acc[nt][q];
            xph[(long)(row0 + g * 4 + q) * 256 + nt * 16 + r] = f2bf(v);
            ps[q][hh] += v * as_v[nt];
            pd[q][hh] += v * ad_v[nt];
        }
    }
    #pragma unroll
    for (int off = 1; off < 16; off <<= 1) {
        #pragma unroll
        for (int q = 0; q < 4; ++q)
            #pragma unroll
            for (int hh = 0; hh < 4; ++hh) {
                ps[q][hh] += __shfl_xor(ps[q][hh], off);
                pd[q][hh] += __shfl_xor(pd[q][hh], off);
            }
    }
    if (r == 0) {
        #pragma unroll
        for (int q = 0; q < 4; ++q) {
            int row = row0 + g * 4 + q;
            #pragma unroll
            for (int hh = 0; hh < 4; ++hh) {
                a_s[row * 4 + hh] = ps[q][hh];
                a_d[row * 4 + hh] = pd[q][hh];
            }
        }
    }
}

// ---------- layer-2 GEMM (bf16 MFMA, bf16 xp2 out) + fused projections ----------
__global__ __launch_bounds__(256) void gemm2_mfma(
        const unsigned short* __restrict__ hb,
        const unsigned short* __restrict__ w2t,
        const float* __restrict__ att_s, const float* __restrict__ att_d,
        unsigned short* __restrict__ xp2h,
        float* __restrict__ a_s, float* __restrict__ a_d, int M) {
    int wave = (int)(((long)blockIdx.x * 256 + threadIdx.x) >> 6);
    int lane = threadIdx.x & 63;
    int row0 = wave * 16;
    if (row0 >= M) return;
    int r = lane & 15;
    int g = lane >> 4;
    bf16x8 a[8];
    const unsigned short* arow = hb + (long)(row0 + r) * 256 + g * 8;
    #pragma unroll
    for (int k0 = 0; k0 < 8; ++k0)
        a[k0] = *(const bf16x8*)(arow + k0 * 32);
    float as_v[2], ad_v[2];
    #pragma unroll
    for (int nt = 0; nt < 2; ++nt) {
        as_v[nt] = att_s[nt * 16 + r];
        ad_v[nt] = att_d[nt * 16 + r];
    }
    f32x4 acc[2];
    acc[0] = (f32x4){0.f, 0.f, 0.f, 0.f};
    acc[1] = (f32x4){0.f, 0.f, 0.f, 0.f};
    #pragma unroll
    for (int nt = 0; nt < 2; ++nt) {
        const unsigned short* brow = w2t + (long)(nt * 16 + r) * 256 + g * 8;
        #pragma unroll
        for (int k0 = 0; k0 < 8; ++k0) {
            bf16x8 b = *(const bf16x8*)(brow + k0 * 32);
            acc[nt] = __builtin_amdgcn_mfma_f32_16x16x32_bf16(a[k0], b, acc[nt], 0, 0, 0);
        }
    }
    float ps[4] = {}, pd[4] = {};
    #pragma unroll
    for (int nt = 0; nt < 2; ++nt) {
        #pragma unroll
        for (int q = 0; q < 4; ++q) {
            float v = acc[nt][q];
            xp2h[(long)(row0 + g * 4 + q) * 32 + nt * 16 + r] = f2bf(v);
            ps[q] += v * as_v[nt];
            pd[q] += v * ad_v[nt];
        }
    }
    #pragma unroll
    for (int off = 1; off < 16; off <<= 1) {
        #pragma unroll
        for (int q = 0; q < 4; ++q) {
            ps[q] += __shfl_xor(ps[q], off);
            pd[q] += __shfl_xor(pd[q], off);
        }
    }
    if (r == 0) {
        #pragma unroll
        for (int q = 0; q < 4; ++q) {
            a_s[row0 + g * 4 + q] = ps[q];
            a_d[row0 + g * 4 + q] = pd[q];
        }
    }
}

// ---------- CSR scan ----------
__global__ __launch_bounds__(256) void scan_local(const int* __restrict__ deg,
        int* __restrict__ rowptr, int* __restrict__ blocksum, int N) {
    __shared__ int part[256];
    int b = blockIdx.x, t = threadIdx.x;
    int base = b * 1024 + t * 4;
    int4 v = make_int4(0, 0, 0, 0);
    if (base + 3 < N) {
        v = *(const int4*)(deg + base);
    } else {
        if (base + 0 < N) v.x = deg[base + 0];
        if (base + 1 < N) v.y = deg[base + 1];
        if (base + 2 < N) v.z = deg[base + 2];
        if (base + 3 < N) v.w = deg[base + 3];
    }
    part[t] = v.x + v.y + v.z + v.w;
    __syncthreads();
    #pragma unroll
    for (int off = 1; off < 256; off <<= 1) {
        int val = (t >= off) ? part[t - off] : 0;
        __syncthreads();
        part[t] += val;
        __syncthreads();
    }
    if (t == 255) blocksum[b] = part[255];
    int r0 = (t > 0) ? part[t - 1] : 0;
    int r1 = r0 + v.x;
    int r2 = r1 + v.y;
    int r3 = r2 + v.z;
    if (base + 3 < N) {
        *(int4*)(rowptr + base) = make_int4(r0, r1, r2, r3);
    } else {
        if (base + 0 < N) rowptr[base + 0] = r0;
        if (base + 1 < N) rowptr[base + 1] = r1;
        if (base + 2 < N) rowptr[base + 2] = r2;
        if (base + 3 < N) rowptr[base + 3] = r3;
    }
}

__global__ __launch_bounds__(256) void scan_add(int* __restrict__ rowptr,
        const int* __restrict__ blocksum, int* __restrict__ cursor,
        int N, int Etot, int nb) {
    __shared__ int part[256];
    int b = blockIdx.x, t = threadIdx.x;
    part[t] = (t < nb) ? blocksum[t] : 0;
    __syncthreads();
    #pragma unroll
    for (int off = 1; off < 256; off <<= 1) {
        int val = (t >= off) ? part[t - off] : 0;
        __syncthreads();
        part[t] += val;
        __syncthreads();
    }
    int off_b = (b > 0) ? part[b - 1] : 0;
    int base = b * 1024 + t * 4;
    if (base + 3 < N) {
        int4 v = *(const int4*)(rowptr + base);
        v.x += off_b; v.y += off_b; v.z += off_b; v.w += off_b;
        *(int4*)(rowptr + base) = v;
        *(int4*)(cursor + base) = v;
    } else {
        for (int i = 0; i < 4; ++i) {
            if (base + i < N) {
                int v = rowptr[base + i] + off_b;
                rowptr[base + i] = v;
                cursor[base + i] = v;
            }
        }
    }
    if (b == 0 && t == 0) rowptr[N] = Etot;
}

__global__ __launch_bounds__(256) void scatter_edges(const int* __restrict__ ei,
        int E, int Etot, int* __restrict__ cursor, int* __restrict__ csr_src) {
    int e = blockIdx.x * 256 + threadIdx.x;
    if (e >= Etot) return;
    int s, d;
    if (e < E) { s = ei[e]; d = ei[E + e]; } else { s = e - E; d = s; }
    int pos = atomicAdd(&cursor[d], 1);
    csr_src[pos] = s;
}

// ---------- helpers ----------
__device__ __forceinline__ void merge_ms(float& m, float& s, float m2, float s2) {
    float mn = fmaxf(m, m2);
    s = s * expf(m - mn) + s2 * expf(m2 - mn);
    m = mn;
}

// ---------- layer-1: row-sort (canonicalize) + two-pass softmax + gather ----------
// wave per node, 4 nodes/block.
// Sweeps use WAVE-UNIFORM iteration counts with clamped shuffle indices so every
// __shfl executes fully converged.
__global__ __launch_bounds__(256) void agg1_fused(const int* __restrict__ rowptr,
        int* __restrict__ csr_src, const float* __restrict__ a_s,
        const float* __restrict__ a_d, const ushort4* __restrict__ xph4,
        const float* __restrict__ bias, ushort4* __restrict__ hb4, int N) {
    __shared__ int shmem[4][512];   // 8 KB: sort scratch, then e-coeff buffer
    unsigned short (*cbuf)[1024] = (unsigned short (*)[1024])shmem;
    int t = threadIdx.x;
    int w = t >> 6;
    int lane = t & 63;
    int d = blockIdx.x * 4 + w;
    if (d >= N) return;            // wave-uniform exit
    int row0 = rowptr[d];
    int deg = rowptr[d + 1] - row0;

    // ---- canonicalize this row (ascending src) ----
    int sv = 0x7FFFFFFF;
    bool reg_sorted = (deg <= 64);
    if (reg_sorted) {
        if (lane < deg) sv = csr_src[row0 + lane];
        #pragma unroll
        for (int k = 2; k <= 64; k <<= 1) {
            for (int jj = k >> 1; jj > 0; jj >>= 1) {
                int u = __shfl_xor(sv, jj);
                bool up = ((lane & k) == 0);
                bool lower = ((lane & jj) == 0);
                int mn = min(sv, u), mx = max(sv, u);
                sv = (up == lower) ? mn : mx;
            }
        }
        if (lane < deg) csr_src[row0 + lane] = sv;     // agg2 reads sorted
    } else if (deg <= 256) {
        for (int j = lane; j < deg; j += 64) shmem[w][j] = csr_src[row0 + j];
        for (int it = 0; it < deg; ++it) {
            int start = it & 1;
            #pragma unroll
            for (int rep = 0; rep < 2; ++rep) {
                int k = start + 2 * lane + rep * 128;
                if (k + 1 < deg) {
                    int a = shmem[w][k], b = shmem[w][k + 1];
                    if (a > b) { shmem[w][k] = b; shmem[w][k + 1] = a; }
                }
            }
        }
        for (int j = lane; j < deg; j += 64) csr_src[row0 + j] = shmem[w][j];
    } else if (lane == 0) {
        for (int i = 1; i < deg; ++i) {
            int key = csr_src[row0 + i];
            int k = i - 1;
            while (k >= 0 && csr_src[row0 + k] > key) {
                csr_src[row0 + k + 1] = csr_src[row0 + k];
                --k;
            }
            csr_src[row0 + k + 1] = key;
        }
    }

    int h = lane & 3;
    int j0 = lane >> 2;
    float ad = a_d[d * 4 + h];
    int iters = (deg + 15) >> 4;   // wave-uniform sweep iteration count
    // sweep 1: max of raw a_s (converged shfl, clamped index)
    float mraw = NEG_SENT;
    for (int it = 0; it < iters; ++it) {
        int j = j0 + (it << 4);
        int jc = (j < deg) ? j : 0;            // deg >= 1 (self-loop)
        int sn = reg_sorted ? __shfl(sv, jc) : csr_src[row0 + jc];
        if (j < deg) mraw = fmaxf(mraw, a_s[sn * 4 + h]);
    }
    #pragma unroll
    for (int off = 4; off <= 32; off <<= 1) mraw = fmaxf(mraw, __shfl_xor(mraw, off));
    float m = mraw + ad;
    m = m > 0.f ? m : 0.2f * m;    // = max_j leaky(a_s_j + ad), by monotonicity
    // sweep 2: e = exp(l - m) -> LDS bf16, sum (converged shfl)
    float s = 0.f;
    for (int it = 0; it < iters; ++it) {
        int j = j0 + (it << 4);
        int jc = (j < deg) ? j : 0;
        int sn = reg_sorted ? __shfl(sv, jc) : csr_src[row0 + jc];
        if (j < deg) {
            float l = a_s[sn * 4 + h] + ad;
            l = l > 0.f ? l : 0.2f * l;
            float e = expf(l - m);
            if (j < 256) cbuf[w][j * 4 + h] = f2bf(e);
            s += e;
        }
    }
    #pragma unroll
    for (int off = 4; off <= 32; off <<= 1) s += __shfl_xor(s, off);
    float inv = 1.f / (s + 1e-16f);
    int hsel = lane >> 4;
    float m_h   = __shfl(m, hsel);
    float inv_h = __shfl(inv, hsel);
    float ad_h  = __shfl(ad, hsel);
    // phase 2: gather (uniform loops -> converged shfl)
    int cap = deg < 256 ? deg : 256;
    float4 acc = make_float4(0.f, 0.f, 0.f, 0.f);
    int j = 0;
    for (; j + 4 <= cap; j += 4) {
        int s0 = reg_sorted ? __shfl(sv, j + 0) : csr_src[row0 + j + 0];
        int s1 = reg_sorted ? __shfl(sv, j + 1) : csr_src[row0 + j + 1];
        int s2 = reg_sorted ? __shfl(sv, j + 2) : csr_src[row0 + j + 2];
        int s3 = reg_sorted ? __shfl(sv, j + 3) : csr_src[row0 + j + 3];
        float c0 = bf2f(cbuf[w][(j + 0) * 4 + hsel]);
        float c1 = bf2f(cbuf[w][(j + 1) * 4 + hsel]);
        float c2 = bf2f(cbuf[w][(j + 2) * 4 + hsel]);
        float c3 = bf2f(cbuf[w][(j + 3) * 4 + hsel]);
        ushort4 u0 = xph4[(long)s0 * 64 + lane];
        ushort4 u1 = xph4[(long)s1 * 64 + lane];
        ushort4 u2 = xph4[(long)s2 * 64 + lane];
        ushort4 u3 = xph4[(long)s3 * 64 + lane];
        acc.x += c0 * bf2f(u0.x); acc.y += c0 * bf2f(u0.y);
        acc.z += c0 * bf2f(u0.z); acc.w += c0 * bf2f(u0.w);
        acc.x += c1 * bf2f(u1.x); acc.y += c1 * bf2f(u1.y);
        acc.z += c1 * bf2f(u1.z); acc.w += c1 * bf2f(u1.w);
        acc.x += c2 * bf2f(u2.x); acc.y += c2 * bf2f(u2.y);
        acc.z += c2 * bf2f(u2.z); acc.w += c2 * bf2f(u2.w);
        acc.x += c3 * bf2f(u3.x); acc.y += c3 * bf2f(u3.y);
        acc.z += c3 * bf2f(u3.z); acc.w += c3 * bf2f(u3.w);
    }
    for (; j < deg; ++j) {
        int sn = reg_sorted ? __shfl(sv, j) : csr_src[row0 + j];
        float c;
        if (j < 256) {
            c = bf2f(cbuf[w][j * 4 + hsel]);
        } else {   // overflow fallback (deg > 256; not hit in practice)
            float l = a_s[sn * 4 + hsel] + ad_h;
            l = l > 0.f ? l : 0.2f * l;
            c = bf2f(f2bf(expf(l - m_h)));
        }
        ushort4 u = xph4[(long)sn * 64 + lane];
        acc.x += c * bf2f(u.x); acc.y += c * bf2f(u.y);
        acc.z += c * bf2f(u.z); acc.w += c * bf2f(u.w);
    }
    float4 b = ((const float4*)bias)[lane];
    float vx = acc.x * inv_h + b.x; vx = vx > 0.f ? vx : expm1f(vx);
    float vy = acc.y * inv_h + b.y; vy = vy > 0.f ? vy : expm1f(vy);
    float vz = acc.z * inv_h + b.z; vz = vz > 0.f ? vz : expm1f(vz);
    float vw = acc.w * inv_h + b.w; vw = vw > 0.f ? vw : expm1f(vw);
    ushort4 o;
    o.x = f2bf(vx); o.y = f2bf(vy); o.z = f2bf(vz); o.w = f2bf(vw);
    hb4[(long)d * 64 + lane] = o;
}

// ---------- layer-2: fused two-pass softmax + gather + row softmax ----------
__global__ __launch_bounds__(256) void agg2_fused(const int* __restrict__ rowptr,
        const int* __restrict__ csr_src, const float* __restrict__ a_s,
        const float* __restrict__ a_d, const unsigned short* __restrict__ xp2h,
        const float* __restrict__ bias, float* __restrict__ out, int N) {
    __shared__ unsigned short ebuf[8][256];     // e bf16 (4 KB)
    int t = threadIdx.x;
    int w2 = t >> 5;
    int d = blockIdx.x * 8 + w2;
    if (d >= N) return;
    int c = t & 31;
    int row0 = rowptr[d];
    int deg = rowptr[d + 1] - row0;
    float ad = a_d[d];
    // sweep 1: max of raw a_s (plain loads; divergence harmless)
    float mraw = NEG_SENT;
    for (int j = c; j < deg; j += 32) {
        int sn = csr_src[row0 + j];
        mraw = fmaxf(mraw, a_s[sn]);
    }
    #pragma unroll
    for (int off = 1; off <= 16; off <<= 1) mraw = fmaxf(mraw, __shfl_xor(mraw, off, 32));
    float m = mraw + ad;
    m = m > 0.f ? m : 0.2f * m;
    // sweep 2: e = exp(l - m), store bf16, sum
    float s = 0.f;
    for (int j = c; j < deg; j += 32) {
        int sn = csr_src[row0 + j];
        float l = a_s[sn] + ad;
        l = l > 0.f ? l : 0.2f * l;
        float e = expf(l - m);
        if (j < 256) ebuf[w2][j] = f2bf(e);
        s += e;
    }
    #pragma unroll
    for (int off = 1; off <= 16; off <<= 1) s += __shfl_xor(s, off, 32);
    float inv = 1.f / (s + 1e-16f);
    // phase 2: gather with unnormalized e; inv folded at end
    int cap = deg < 256 ? deg : 256;
    float acc = 0.f;
    int j = 0;
    for (; j + 4 <= cap; j += 4) {
        long e0 = row0 + j;
        int s0 = csr_src[e0 + 0];
        int s1 = csr_src[e0 + 1];
        int s2 = csr_src[e0 + 2];
        int s3 = csr_src[e0 + 3];
        float c0 = bf2f(ebuf[w2][j + 0]);
        float c1 = bf2f(ebuf[w2][j + 1]);
        float c2 = bf2f(ebuf[w2][j + 2]);
        float c3 = bf2f(ebuf[w2][j + 3]);
        float v0 = bf2f(xp2h[(long)s0 * 32 + c]);
        float v1 = bf2f(xp2h[(long)s1 * 32 + c]);
        float v2 = bf2f(xp2h[(long)s2 * 32 + c]);
        float v3 = bf2f(xp2h[(long)s3 * 32 + c]);
        acc += c0 * v0;
        acc += c1 * v1;
        acc += c2 * v2;
        acc += c3 * v3;
    }
    for (; j < deg; ++j) {
        long e = row0 + j;
        int sn = csr_src[e];
        float co;
        if (j < 256) {
            co = bf2f(ebuf[w2][j]);
        } else {
            float l = a_s[sn] + ad; l = l > 0.f ? l : 0.2f * l;
            co = bf2f(f2bf(expf(l - m)));
        }
        acc += co * bf2f(xp2h[(long)sn * 32 + c]);
    }
    float v = acc * inv + bias[c];
    float mx = v;
    #pragma unroll
    for (int off = 16; off; off >>= 1) mx = fmaxf(mx, __shfl_xor(mx, off, 32));
    float ex = expf(v - mx);
    float sm = ex;
    #pragma unroll
    for (int off = 16; off; off >>= 1) sm += __shfl_xor(sm, off, 32);
    out[(long)d * 32 + c] = ex / sm;
}

// ---------- host ----------
extern "C" void kernel_launch(void* const* d_in, const int* in_sizes, int n_in,
                              void* d_out, int out_size, void* d_ws, size_t ws_size,
                              hipStream_t stream) {
    const float* x   = (const float*)d_in[0];
    const int*   ei  = (const int*)d_in[1];
    const float* W1  = (const float*)d_in[2];
    const float* as1 = (const float*)d_in[3];
    const float* ad1 = (const float*)d_in[4];
    const float* b1  = (const float*)d_in[5];
    const float* W2  = (const float*)d_in[6];
    const float* as2 = (const float*)d_in[7];
    const float* ad2 = (const float*)d_in[8];
    const float* b2  = (const float*)d_in[9];
    float* out = (float*)d_out;

    const int N = in_sizes[0] / 128;     // 50000
    const int E = in_sizes[1] / 2;       // 640000
    const int Etot = E + N;              // + self loops

    // workspace layout (~60 MB, 16B-aligned blocks)
    unsigned short* xp1h = (unsigned short*)d_ws;        // N*256 bf16
    unsigned short* hb   = xp1h + (long)N * 256;         // N*256 bf16
    unsigned short* w1t  = hb + (long)N * 256;           // 32768 bf16
    unsigned short* w2t  = w1t + 32768;                  // 8192 bf16
    unsigned short* xp2h = w2t + 8192;                   // N*32 bf16
    float* a_s1   = (float*)(xp2h + (long)N * 32);       // N*4
    float* a_d1   = a_s1 + (long)N * 4;                  // N*4
    float* a_s2   = a_d1 + (long)N * 4;                  // N
    float* a_d2   = a_s2 + N;                            // N
    int* deg      = (int*)(a_d2 + N);                    // N
    int* rowptr   = deg + N;                             // N+4 (padded)
    int* cursor   = rowptr + N + 4;                      // N
    int* csr_src  = cursor + N;                          // Etot
    int* blocksum = csr_src + Etot;                      // 256

    hipMemsetAsync(deg, 0, (size_t)N * sizeof(int), stream);

    // ---- CSR build + weight prep ----
    int nbE = (Etot + 255) / 256;
    int nbS = (N + 1023) / 1024;
    prep_count<<<160 + nbE, 256, 0, stream>>>(W1, W2, w1t, w2t, ei, E, Etot, deg);
    scan_local<<<nbS, 256, 0, stream>>>(deg, rowptr, blocksum, N);
    scan_add<<<nbS, 256, 0, stream>>>(rowptr, blocksum, cursor, N, Etot, nbS);
    scatter_edges<<<nbE, 256, 0, stream>>>(ei, E, Etot, cursor, csr_src);

    int gemmBlocks = (((N + 15) / 16) + 3) / 4;   // 4 waves/block

    // ---- layer 1 (agg1 canonicalizes csr_src rows in-kernel) ----
    gemm1_mfma<<<gemmBlocks, 256, 0, stream>>>(x, w1t, as1, ad1,
                                               xp1h, a_s1, a_d1, N);
    agg1_fused<<<(N + 3) / 4, 256, 0, stream>>>(rowptr, csr_src, a_s1, a_d1,
                                                (const ushort4*)xp1h, b1,
                                                (ushort4*)hb, N);

    // ---- layer 2 ----
    gemm2_mfma<<<gemmBlocks, 256, 0, stream>>>(hb, w2t, as2, ad2,
                                               xp2h, a_s2, a_d2, N);
    agg2_fused<<<(N + 7) / 8, 256, 0, stream>>>(rowptr, csr_src, a_s2, a_d2,
                                                xp2h, b2, out, N);
}